// Round 5
// baseline (232.141 us; speedup 1.0000x reference)
//
#include <hip/hip_runtime.h>
#include <hip/hip_bf16.h>

// HelicalAttention on MI355X (gfx950).
// B=2,S=2048,E=1024,H=16,HD=64,HX=64,P=32. All heavy math in bf16 MFMA,
// fp32 accumulate. Score = (q/16)·k + (qs/8)·(ks/8) folded into one K=128
// contraction; log2(e) folded into Q so softmax uses raw exp2. Flash-style,
// no max subtraction (scores bounded).
// R5: attn q-reuse — 4 waves/block, each wave covers 64 q-cols (2 B-frags),
// so every K A-frag / V B-frag LDS read feeds 2 MFMAs. Halves the dominant
// LDS-read traffic at constant wave count (2 blocks x 4 waves per CU).

typedef unsigned short u16;
typedef unsigned int u32;
typedef __attribute__((ext_vector_type(8))) __bf16 bf16x8;
typedef __attribute__((ext_vector_type(4))) float f32x4;
typedef __attribute__((ext_vector_type(16))) float f32x16;

union BFrag { u32 u[4]; bf16x8 b; };

__device__ __forceinline__ u16 f2b(float f) {
  u32 u = __float_as_uint(f);
  u32 r = (u + 0x7fffu + ((u >> 16) & 1u)) >> 16;
  return (u16)r;
}
__device__ __forceinline__ float b2f(u16 h) {
  return __uint_as_float(((u32)h) << 16);
}

__device__ __forceinline__ f32x4 mfma16(bf16x8 a, bf16x8 b, f32x4 c) {
  return __builtin_amdgcn_mfma_f32_16x16x32_bf16(a, b, c, 0, 0, 0);
}
__device__ __forceinline__ f32x16 mfma32(bf16x8 a, bf16x8 b, f32x16 c) {
  return __builtin_amdgcn_mfma_f32_32x32x16_bf16(a, b, c, 0, 0, 0);
}

// async global->LDS, 16B per lane. LDS dest = wave-uniform base + lane*16.
__device__ __forceinline__ void gld16(void* lds, const void* g) {
  __builtin_amdgcn_global_load_lds(
      (const __attribute__((address_space(1))) unsigned int*)g,
      (__attribute__((address_space(3))) unsigned int*)lds, 16, 0, 0);
}

#define LOG2E 1.4426950408889634f

// ---------------------------------------------------------------- cast -----
__global__ __launch_bounds__(256) void cast_kernel(
    const float* __restrict__ x,  const float* __restrict__ wq,
    const float* __restrict__ wk, const float* __restrict__ wv,
    const float* __restrict__ wo, const float* __restrict__ whel,
    u16* __restrict__ xb, u16* __restrict__ wb, u16* __restrict__ wob,
    u16* __restrict__ whb) {
  long long q = (long long)blockIdx.x * 256 + threadIdx.x;
  const float* s; u16* d; long long base;
  if (q < 1048576)      { s = x;    d = xb;            base = 0; }
  else if (q < 1310720) { s = wq;   d = wb;            base = 1048576; }
  else if (q < 1572864) { s = wk;   d = wb + 1048576;  base = 1310720; }
  else if (q < 1835008) { s = wv;   d = wb + 2097152;  base = 1572864; }
  else if (q < 2097152) { s = wo;   d = wob;           base = 1835008; }
  else                  { s = whel; d = whb;           base = 2097152; }
  long long e = (q - base) * 4;
  float4 v = *(const float4*)(s + e);
  ushort4 o;
  o.x = f2b(v.x); o.y = f2b(v.y); o.z = f2b(v.z); o.w = f2b(v.w);
  *(ushort4*)(d + e) = o;
}

// ------------------------------------------------------------ QKV GEMM -----
// which=0 -> Qcat[bh][s][0:64] = q*(log2e/16); which=1 -> Kcat = k;
// which=2 -> vT[bh][d][t] = v via LDS transpose (coalesced stores).
// Double-buffered LDS, prefetch-after-barrier pipeline (1 barrier/K-step).
__global__ __launch_bounds__(256, 3) void qkv_gemm(
    const u16* __restrict__ xb, const u16* __restrict__ wb,
    const float* __restrict__ bq, const float* __restrict__ bk,
    const float* __restrict__ bv,
    u16* __restrict__ Qcat, u16* __restrict__ Kcat, u16* __restrict__ vt) {
  __shared__ u16 Al[2][128][32];
  __shared__ u16 Bl[2][128][32];
  __shared__ u16 T[64][136];  // V transpose staging (epilogue only)
  const int nt = blockIdx.x, mt = blockIdx.y;
  const int which = nt >> 3;
  const int n0 = (nt & 7) << 7;
  const int m0 = mt << 7;
  const int tid = threadIdx.x;
  const int wave = tid >> 6, lane = tid & 63;
  const int g = lane >> 4, c15 = lane & 15;
  const int wm = wave & 1, wn = wave >> 1;
  const u16* Wp = wb + (long long)which * (1024 * 1024) + n0 * 1024;
  const u16* Ap = xb + m0 * 1024;
  const int srow = (wave * 64 + lane) >> 2;  // 0..63
  const int scol = (lane & 3) << 3;          // 0,8,16,24

  f32x4 acc[4][4];
#pragma unroll
  for (int i = 0; i < 4; i++)
#pragma unroll
    for (int j = 0; j < 4; j++) acc[i][j] = f32x4{0.f, 0.f, 0.f, 0.f};

  // prologue: stage k0=0 into buf 0
  gld16(&Al[0][srow][scol],      Ap + srow * 1024 + scol);
  gld16(&Al[0][64 + srow][scol], Ap + (64 + srow) * 1024 + scol);
  gld16(&Bl[0][srow][scol],      Wp + srow * 1024 + scol);
  gld16(&Bl[0][64 + srow][scol], Wp + (64 + srow) * 1024 + scol);

  for (int k0 = 0; k0 < 1024; k0 += 32) {
    const int c = (k0 >> 5) & 1;
    __syncthreads();  // waits DMA(k0); prefetch below had full compute to land
    if (k0 + 32 < 1024) {
      const int kn = k0 + 32;
      gld16(&Al[c ^ 1][srow][scol],      Ap + srow * 1024 + kn + scol);
      gld16(&Al[c ^ 1][64 + srow][scol], Ap + (64 + srow) * 1024 + kn + scol);
      gld16(&Bl[c ^ 1][srow][scol],      Wp + srow * 1024 + kn + scol);
      gld16(&Bl[c ^ 1][64 + srow][scol], Wp + (64 + srow) * 1024 + kn + scol);
    }
    bf16x8 a[4], b[4];
#pragma unroll
    for (int i = 0; i < 4; i++)
      a[i] = *(const bf16x8*)&Al[c][wm * 64 + i * 16 + c15][g * 8];
#pragma unroll
    for (int j = 0; j < 4; j++)
      b[j] = *(const bf16x8*)&Bl[c][wn * 64 + j * 16 + c15][g * 8];
#pragma unroll
    for (int i = 0; i < 4; i++)
#pragma unroll
      for (int j = 0; j < 4; j++) acc[i][j] = mfma16(a[i], b[j], acc[i][j]);
  }

  if (which == 2) {
#pragma unroll
    for (int half = 0; half < 2; ++half) {
      __syncthreads();
      if (wn == half) {
#pragma unroll
        for (int i = 0; i < 4; i++)
#pragma unroll
          for (int j = 0; j < 4; j++)
#pragma unroll
            for (int r = 0; r < 4; r++) {
              int nloc = j * 16 + c15;                  // 0..63
              int mloc = wm * 64 + i * 16 + g * 4 + r;  // 0..127
              float v = acc[i][j][r] + bv[n0 + half * 64 + nloc];
              T[nloc][mloc] = f2b(v);
            }
      }
      __syncthreads();
#pragma unroll
      for (int it = 0; it < 4; ++it) {
        int idx = it * 256 + tid;
        int row = idx >> 4;         // 0..63
        int cm = (idx & 15) * 8;    // 0..120
        int col = n0 + half * 64 + row;
        int hh = col >> 6, dd = col & 63;
        int m = m0 + cm;
        int bb2 = m >> 11, s = m & 2047;
        *(uint4*)&vt[(((bb2 * 16 + hh) * 64) + dd) * 2048 + s] =
            *(const uint4*)&T[row][cm];
      }
    }
    return;
  }

  const float* bias = (which == 0) ? bq : bk;
#pragma unroll
  for (int i = 0; i < 4; i++)
#pragma unroll
    for (int j = 0; j < 4; j++)
#pragma unroll
      for (int r = 0; r < 4; r++) {
        int row = m0 + wm * 64 + i * 16 + g * 4 + r;  // token 0..4095
        int col = n0 + wn * 64 + j * 16 + c15;        // 0..1023
        float v = acc[i][j][r] + bias[col];
        int bb = row >> 11, s = row & 2047;
        int hh = col >> 6, d = col & 63;
        if (which == 0) {
          Qcat[(((bb * 16 + hh) * 2048) + s) * 128 + d] =
              f2b(v * (0.0625f * LOG2E));
        } else {
          Kcat[(((bb * 16 + hh) * 2048) + s) * 128 + d] = f2b(v);
        }
      }
}

// ------------------------------------------------------------- helical -----
// Q-side outputs carry an extra log2e (K-side plain), matching qkv fold.
__global__ __launch_bounds__(256, 2) void helical_kernel(
    u16* __restrict__ Qcat, u16* __restrict__ Kcat,
    const u16* __restrict__ whb, const float* __restrict__ bhel) {
  __shared__ u16 A[2][2][64][32];  // [q/k][kq][row][32]
  __shared__ u16 Wl[2][64][32];    // Whel[h] bf16, [kq][e][32]
  const int sb = blockIdx.x, bh = blockIdx.y;
  const int h = bh & 15;
  const int s0 = sb << 6;
  const int tid = threadIdx.x;
  const int wave = tid >> 6, lane = tid & 63;
  const int g = lane >> 4, c15 = lane & 15;
  u16* Qb = Qcat + (long long)bh * (2048 * 128);
  u16* Kb = Kcat + (long long)bh * (2048 * 128);

#pragma unroll
  for (int it = 0; it < 2; ++it) {  // stage Whel[h]
    int cidx = it * 256 + tid;
    int e = cidx >> 3, ds = (cidx & 7) << 3;
    uint4 vv = *(const uint4*)(whb + h * 4096 + e * 64 + ds);
    *(uint4*)&Wl[ds >> 5][e][ds & 31] = vv;
  }
#pragma unroll
  for (int it = 0; it < 4; ++it) {  // stage q (undo fold) and k rows
    int cidx = it * 256 + tid;
    int which = cidx >> 9;
    int r = (cidx >> 3) & 63;
    int ds = (cidx & 7) << 3;
    const u16* src = (which ? Kb : Qb) + (s0 + r) * 128 + ds;
    uint4 vv = *(const uint4*)src;
    if (which == 0) {
      u16 tmp[8];
      *(uint4*)tmp = vv;
#pragma unroll
      for (int q = 0; q < 8; ++q)
        tmp[q] = f2b(b2f(tmp[q]) * (16.0f / LOG2E));
      vv = *(uint4*)tmp;
    }
    *(uint4*)&A[which][ds >> 5][r][ds & 31] = vv;
  }
  __syncthreads();

  const int which = wave >> 1, hf = wave & 1;
  f32x4 acc[2][4];
#pragma unroll
  for (int i = 0; i < 2; i++)
#pragma unroll
    for (int j = 0; j < 4; j++) acc[i][j] = f32x4{0.f, 0.f, 0.f, 0.f};
#pragma unroll
  for (int kq = 0; kq < 2; ++kq) {
    bf16x8 a0 = *(const bf16x8*)&A[which][kq][hf * 32 + c15][g * 8];
    bf16x8 a1 = *(const bf16x8*)&A[which][kq][hf * 32 + 16 + c15][g * 8];
#pragma unroll
    for (int j = 0; j < 4; ++j) {
      bf16x8 bb = *(const bf16x8*)&Wl[kq][j * 16 + c15][g * 8];
      acc[0][j] = mfma16(a0, bb, acc[0][j]);
      acc[1][j] = mfma16(a1, bb, acc[1][j]);
    }
  }
  u16* Dst = which ? Kb : Qb;
  const float oscale = which ? 0.125f : (0.125f * LOG2E);
#pragma unroll
  for (int i = 0; i < 2; ++i)
#pragma unroll
    for (int j = 0; j < 4; ++j)
#pragma unroll
      for (int r = 0; r < 4; ++r) {
        int s_loc = hf * 32 + i * 16 + g * 4 + r;
        int e = j * 16 + c15;
        float v = acc[i][j][r] + bhel[h * 64 + e];
        float pp = __shfl_xor(v, 1);  // pair partner (e^1), same row
        float nn = sqrtf(v * v + pp * pp);
        float o = v / fmaxf(nn, 1e-12f) * oscale;
        int s = s0 + s_loc;
        int u = s >> 1, c2 = s & 1;
        int row_out = ((e & 1) ? 1024 : 0) + u;
        int col_out = 64 + (e & ~1) + c2;
        Dst[row_out * 128 + col_out] = f2b(o);
      }
}

// ----------------------------------------------------------- attention -----
// Per (bh, 128-q tile), 4 waves: wq2=w&1 (64-q half), wt=w>>1 (32-t half).
// Each wave: 2 Q B-frag sets (qh=0,1) so every K A-frag / V B-frag LDS read
// feeds 2 MFMAs. Pipelined single-barrier K-loop over 32 tiles of 64 t.
// P kept in registers (shfl_xor(32) C->A relayout); per-wave den scalars;
// cross-wt O partial sum at the end via LDS (Kl reused: 32KB = 128x64 f32).
// LDS = 32K (Kl) + 16K (Vl) + 1K (denl) = 49 KB; grid 512 -> 2 blocks/CU.
__global__ __launch_bounds__(256, 2) void attn_kernel(
    const u16* __restrict__ Qcat, const u16* __restrict__ Kcat,
    const u16* __restrict__ vt, u16* __restrict__ AO) {
  __shared__ u16 Kl[2][64][128];   // [buf][t-row][cat 16 chunks, swizzled]
  __shared__ u16 Vl[2][64][64];    // [buf][d-row][t 8 chunks, swizzled]
  __shared__ float denl[2][128];   // [wt][q-local]
  const int qt = blockIdx.x, bh = blockIdx.y;
  const int bb = bh >> 4, h = bh & 15;
  const int q0 = qt << 7;
  const int tid = threadIdx.x;
  const int w = tid >> 6, lane = tid & 63;
  const int wq2 = w & 1, wt = w >> 1;
  const int l31 = lane & 31, l5 = lane >> 5;
  const u16* Qb = Qcat + (long long)bh * (2048 * 128);
  const u16* Kb = Kcat + (long long)bh * (2048 * 128);
  const u16* Vb = vt + (long long)bh * (64 * 2048);

  // Q B-frags: qh half: q = q0 + 64*wq2 + 32*qh + l31; k = ks*16 + l5*8 + j
  bf16x8 qf[2][8];
#pragma unroll
  for (int qh = 0; qh < 2; ++qh) {
    const u16* qrow = Qb + (q0 + 64 * wq2 + 32 * qh + l31) * 128 + l5 * 8;
#pragma unroll
    for (int ks = 0; ks < 8; ++ks)
      qf[qh][ks] = *(const bf16x8*)(qrow + ks * 16);
  }

  // staging address precompute (XOR-swizzled 16B chunks), 256 threads
  // K: 4 rounds of 256 chunk-slots; V: 2 rounds.
  int krowR[4], ksrcR[4];
#pragma unroll
  for (int rk = 0; rk < 4; ++rk) {
    int id = rk * 256 + tid;
    int row = id >> 4, kp = id & 15;
    krowR[rk] = row;
    ksrcR[rk] = (kp & 8) | ((kp & 7) ^ (row & 7));
  }
  int vdR[2], vsrcR[2];
#pragma unroll
  for (int rv = 0; rv < 2; ++rv) {
    int id = rv * 256 + tid;
    int d = id >> 3;
    vdR[rv] = d;
    vsrcR[rv] = (id & 7) ^ (d & 7);
  }

  // prologue: stage tile 0 into buf 0
#pragma unroll
  for (int rk = 0; rk < 4; ++rk)
    gld16(((u16*)Kl[0]) + (rk * 256 + tid) * 8,
          Kb + krowR[rk] * 128 + ksrcR[rk] * 8);
#pragma unroll
  for (int rv = 0; rv < 2; ++rv)
    gld16(((u16*)Vl[0]) + (rv * 256 + tid) * 8,
          Vb + vdR[rv] * 2048 + vsrcR[rv] * 8);

  f32x16 accO[2][2];  // [qh][dq]
#pragma unroll
  for (int a = 0; a < 2; ++a)
#pragma unroll
    for (int b = 0; b < 2; ++b)
#pragma unroll
      for (int i = 0; i < 16; ++i) accO[a][b][i] = 0.f;
  float den[2] = {0.f, 0.f};

  const int krow = 32 * wt + l31;  // S-phase A row (t-local)
  const int kr7 = krow & 7;

  for (int t = 0; t < 32; ++t) {
    const int cur = t & 1;
    __syncthreads();  // DMA(tile t) complete; readers of buf cur^1 done
    if (t + 1 < 32) {
      const int t1 = (t + 1) << 6;
      u16* Kd = (u16*)Kl[cur ^ 1];
      u16* Vd = (u16*)Vl[cur ^ 1];
#pragma unroll
      for (int rk = 0; rk < 4; ++rk)
        gld16(Kd + (rk * 256 + tid) * 8,
              Kb + (t1 + krowR[rk]) * 128 + ksrcR[rk] * 8);
#pragma unroll
      for (int rv = 0; rv < 2; ++rv)
        gld16(Vd + (rv * 256 + tid) * 8,
              Vb + vdR[rv] * 2048 + t1 + vsrcR[rv] * 8);
    }

    // ---- S^T[t 32wt..][q 64wq2..+64] : 8 k-steps; each A read -> 2 MFMAs
    f32x16 accS0, accS1;
#pragma unroll
    for (int i = 0; i < 16; ++i) { accS0[i] = 0.f; accS1[i] = 0.f; }
#pragma unroll
    for (int ks = 0; ks < 8; ++ks) {
      int lc = 2 * ks + l5;
      int p = (lc & 8) | ((lc & 7) ^ kr7);
      bf16x8 ak = *(const bf16x8*)&Kl[cur][krow][p * 8];
      accS0 = mfma32(ak, qf[0][ks], accS0);
      accS1 = mfma32(ak, qf[1][ks], accS1);
    }

    // ---- exp2 -> packed bf16 P (regs); relayout C->A via shfl_xor(32)
    BFrag PA[2][2];  // [qh][ks]
#pragma unroll
    for (int qh = 0; qh < 2; ++qh) {
      const f32x16& s = qh ? accS1 : accS0;
      u32 D0[2], D1[2], D2[2], D3[2];
#pragma unroll
      for (int rr = 0; rr < 4; ++rr) {
        float p0 = __builtin_amdgcn_exp2f(s[4 * rr + 0]);
        float p1 = __builtin_amdgcn_exp2f(s[4 * rr + 1]);
        float p2 = __builtin_amdgcn_exp2f(s[4 * rr + 2]);
        float p3 = __builtin_amdgcn_exp2f(s[4 * rr + 3]);
        den[qh] += (p0 + p1) + (p2 + p3);
        u32 lo =
            (__float_as_uint(p0) >> 16) | (__float_as_uint(p1) & 0xffff0000u);
        u32 hi =
            (__float_as_uint(p2) >> 16) | (__float_as_uint(p3) & 0xffff0000u);
        if (rr == 0) { D0[0] = lo; D0[1] = hi; }
        else if (rr == 1) { D1[0] = lo; D1[1] = hi; }
        else if (rr == 2) { D2[0] = lo; D2[1] = hi; }
        else { D3[0] = lo; D3[1] = hi; }
      }
      u32 e00 = __shfl_xor((int)D0[0], 32), e01 = __shfl_xor((int)D0[1], 32);
      u32 e10 = __shfl_xor((int)D1[0], 32), e11 = __shfl_xor((int)D1[1], 32);
      u32 e20 = __shfl_xor((int)D2[0], 32), e21 = __shfl_xor((int)D2[1], 32);
      u32 e30 = __shfl_xor((int)D3[0], 32), e31 = __shfl_xor((int)D3[1], 32);
      PA[qh][0].u[0] = l5 ? e10 : D0[0];
      PA[qh][0].u[1] = l5 ? e11 : D0[1];
      PA[qh][0].u[2] = l5 ? D1[0] : e00;
      PA[qh][0].u[3] = l5 ? D1[1] : e01;
      PA[qh][1].u[0] = l5 ? e30 : D2[0];
      PA[qh][1].u[1] = l5 ? e31 : D2[1];
      PA[qh][1].u[2] = l5 ? D3[0] : e20;
      PA[qh][1].u[3] = l5 ? D3[1] : e21;
    }

    // ---- O[qh][dq] += P · V over OWN t-half; each V read -> 2 MFMAs
#pragma unroll
    for (int dq = 0; dq < 2; ++dq) {
      int d = 32 * dq + l31;
      int d7 = d & 7;
#pragma unroll
      for (int ks = 0; ks < 2; ++ks) {
        int lc = 4 * wt + 2 * ks + l5;
        bf16x8 bvf = *(const bf16x8*)&Vl[cur][d][((lc ^ d7) & 7) * 8];
        accO[0][dq] = mfma32(PA[0][ks].b, bvf, accO[0][dq]);
        accO[1][dq] = mfma32(PA[1][ks].b, bvf, accO[1][dq]);
      }
    }
  }

  // ---- den: own-l5 partial + partner = own t-half total; publish per q-col
  den[0] += __shfl_xor(den[0], 32);
  den[1] += __shfl_xor(den[1], 32);
  if (l5 == 0) {
    denl[wt][64 * wq2 + l31] = den[0];
    denl[wt][64 * wq2 + 32 + l31] = den[1];
  }
  __syncthreads();  // denl ready AND all Kl reads done (safe to reuse Kl)

  // ---- cross-wt O reduction via LDS scratch (Kl: 32KB = 128q x 64d f32)
  float* S = (float*)Kl;
  if (wt == 1) {
#pragma unroll
    for (int qh = 0; qh < 2; ++qh)
#pragma unroll
      for (int dq = 0; dq < 2; ++dq)
#pragma unroll
        for (int r = 0; r < 16; ++r) {
          int qr = (r & 3) + 8 * (r >> 2) + 4 * l5;
          S[(64 * wq2 + 32 * qh + qr) * 64 + 32 * dq + l31] = accO[qh][dq][r];
        }
  }
  __syncthreads();
  if (wt == 0) {
#pragma unroll
    for (int qh = 0; qh < 2; ++qh)
#pragma unroll
      for (int r = 0; r < 16; ++r) {
        int qr = (r & 3) + 8 * (r >> 2) + 4 * l5;
        int ql = 64 * wq2 + 32 * qh + qr;
        float inv = 1.0f / (denl[0][ql] + denl[1][ql]);
        long long base = ((long long)(bb * 2048 + q0 + ql) * 1024) + h * 64;
#pragma unroll
        for (int dq = 0; dq < 2; ++dq) {
          float o = (accO[qh][dq][r] + S[ql * 64 + 32 * dq + l31]) * inv;
          AO[base + 32 * dq + l31] = f2b(o);
        }
      }
  }
}

// ----------------------------------------------------------- out GEMM -----
// Double-buffered prefetch-after-barrier pipeline (1 barrier/K-step).
__global__ __launch_bounds__(256, 2) void out_gemm(
    const u16* __restrict__ AO, const u16* __restrict__ wob,
    const float* __restrict__ bo, float* __restrict__ out) {
  __shared__ u16 Al[2][128][32];
  __shared__ u16 Bl[2][128][32];
  const int n0 = blockIdx.x << 7;
  const int m0 = blockIdx.y << 7;
  const int tid = threadIdx.x;
  const int wave = tid >> 6, lane = tid & 63;
  const int g = lane >> 4, c15 = lane & 15;
  const int wm = wave & 1, wn = wave >> 1;
  const u16* Wp = wob + n0 * 1024;
  const u16* Ap = AO + m0 * 1024;
  const int srow = (wave * 64 + lane) >> 2;
  const int scol = (lane & 3) << 3;

  f32x4 acc[4][4];
#pragma unroll
  for (int i = 0; i < 4; i++)
#pragma unroll
    for (int j = 0; j < 4; j++) acc[i][j] = f32x4{0.f, 0.f, 0.f, 0.f};

  gld16(&Al[0][srow][scol],      Ap + srow * 1024 + scol);
  gld16(&Al[0][64 + srow][scol], Ap + (64 + srow) * 1024 + scol);
  gld16(&Bl[0][srow][scol],      Wp + srow * 1024 + scol);
  gld16(&Bl[0][64 + srow][scol], Wp + (64 + srow) * 1024 + scol);

  for (int k0 = 0; k0 < 1024; k0 += 32) {
    const int c = (k0 >> 5) & 1;
    __syncthreads();
    if (k0 + 32 < 1024) {
      const int kn = k0 + 32;
      gld16(&Al[c ^ 1][srow][scol],      Ap + srow * 1024 + kn + scol);
      gld16(&Al[c ^ 1][64 + srow][scol], Ap + (64 + srow) * 1024 + kn + scol);
      gld16(&Bl[c ^ 1][srow][scol],      Wp + srow * 1024 + kn + scol);
      gld16(&Bl[c ^ 1][64 + srow][scol], Wp + (64 + srow) * 1024 + kn + scol);
    }
    bf16x8 a[4], b[4];
#pragma unroll
    for (int i = 0; i < 4; i++)
      a[i] = *(const bf16x8*)&Al[c][wm * 64 + i * 16 + c15][g * 8];
#pragma unroll
    for (int j = 0; j < 4; j++)
      b[j] = *(const bf16x8*)&Bl[c][wn * 64 + j * 16 + c15][g * 8];
#pragma unroll
    for (int i = 0; i < 4; i++)
#pragma unroll
      for (int j = 0; j < 4; j++) acc[i][j] = mfma16(a[i], b[j], acc[i][j]);
  }
#pragma unroll
  for (int i = 0; i < 4; i++)
#pragma unroll
    for (int j = 0; j < 4; j++)
#pragma unroll
      for (int r = 0; r < 4; r++) {
        int row = m0 + wm * 64 + i * 16 + g * 4 + r;
        int col = n0 + wn * 64 + j * 16 + c15;
        out[row * 1024 + col] = acc[i][j][r] + bo[col];
      }
}

// -------------------------------------------------------------- launch -----
extern "C" void kernel_launch(void* const* d_in, const int* in_sizes, int n_in,
                              void* d_out, int out_size, void* d_ws,
                              size_t ws_size, hipStream_t stream) {
  const float* x    = (const float*)d_in[0];
  const float* Wq   = (const float*)d_in[1];
  const float* bq   = (const float*)d_in[2];
  const float* Wk   = (const float*)d_in[3];
  const float* bk   = (const float*)d_in[4];
  const float* Wv   = (const float*)d_in[5];
  const float* bv   = (const float*)d_in[6];
  const float* Wo   = (const float*)d_in[7];
  const float* bo   = (const float*)d_in[8];
  const float* Whel = (const float*)d_in[9];
  const float* bhel = (const float*)d_in[10];
  float* out = (float*)d_out;

  char* ws = (char*)d_ws;
  u16* xb   = (u16*)(ws + 0);                  //  8 MB
  u16* wb   = (u16*)(ws + 8388608);            //  6 MB (Wq|Wk|Wv)
  u16* wob  = (u16*)(ws + 14680064);           //  2 MB
  u16* whb  = (u16*)(ws + 16777216);           //  128 KB
  u16* Qcat = (u16*)(ws + 16908288);           // 16 MB  [bh][s][128]
  u16* Kcat = (u16*)(ws + 33685504);           // 16 MB
  u16* vt   = (u16*)(ws + 50462720);           //  8 MB  [bh][d][t]
  u16* AO   = (u16*)(ws + 58851328);           //  8 MB  (total ~64.1 MB)

  cast_kernel<<<dim3(8256), dim3(256), 0, stream>>>(x, Wq, Wk, Wv, Wo, Whel,
                                                    xb, wb, wob, whb);
  qkv_gemm<<<dim3(24, 32), dim3(256), 0, stream>>>(xb, wb, bq, bk, bv, Qcat,
                                                   Kcat, vt);
  helical_kernel<<<dim3(32, 32), dim3(256), 0, stream>>>(Qcat, Kcat, whb,
                                                         bhel);
  attn_kernel<<<dim3(16, 32), dim3(256), 0, stream>>>(Qcat, Kcat, vt, AO);
  out_gemm<<<dim3(8, 32), dim3(256), 0, stream>>>(AO, wob, bo, out);
}